// Round 4
// baseline (445.152 us; speedup 1.0000x reference)
//
#include <hip/hip_runtime.h>

// TTRFluxLayer R7: phi v5 — small blocks, spill-free by construction.
// Invariant learned R5/R6: acc/lane = tile_elems/threads; 128x256@512thr = 64 acc
// + ~90 arch can never fit 128-reg (2-block) budget. Fix: 32-row tile @ 256 thr
// -> 32 acc/lane, ~100 total regs, LDS 16.9KB -> 4+ blocks/CU, 4-wave barriers,
// deep inter-block interleave. launch_bounds(256,4)=cap 128 (no forced spill).
// kpT REMOVED from phi: s_kernel now stages kp with an in-LDS transpose
// (XOR-swizzled s-index; linear kt would be a 32-way write conflict).
// Saves 48MB HBM write + phi's whole transposed epilogue.
// ws: w1h 64K | w2h 128K | qp 48M | kp 48M | Wf 48M | S/Wr 48M | vT 24M

typedef __attribute__((ext_vector_type(8))) _Float16 f16x8;
typedef __attribute__((ext_vector_type(4))) _Float16 f16x4;
typedef __attribute__((ext_vector_type(4))) float f32x4;

#define MFMA16(a, b, c) __builtin_amdgcn_mfma_f32_16x16x32_f16((a), (b), (c), 0, 0, 0)

constexpr int BH   = 24;
constexpr int NSEQ = 4096;
constexpr int DD   = 128;
constexpr int FF   = 256;
constexpr int CHK  = 128;
constexpr int NC   = NSEQ / CHK;     // 32
constexpr int NROWS = BH * NSEQ;     // 98304

// ---------------- k0: weight convert ----------------
__global__ void prep_kernel(const float* __restrict__ w1, const float* __restrict__ w2,
                            _Float16* __restrict__ w1h, _Float16* __restrict__ w2h) {
  int i = blockIdx.x * 256 + threadIdx.x;
  if (i < FF * DD) w1h[i] = (_Float16)w1[i];
  if (i < FF * FF) w2h[i] = (_Float16)w2[i];
}

// ---------------- k0b: v -> vT fp16 [bh][d][s] ----------------
__global__ void vt_kernel(const float* __restrict__ v, _Float16* __restrict__ vT) {
  __shared__ __align__(16) _Float16 lt[128][136];
  int blk = blockIdx.x;
  int c = blk & 31, bh = blk >> 5;
  const float* vc = v + ((size_t)bh * NSEQ + c * CHK) * DD;
  int tid = threadIdx.x;
#pragma unroll
  for (int it = 0; it < 16; ++it) {
    int flat = it * 1024 + tid * 4;  // 128s x 128d
    int s = flat >> 7, d0 = flat & 127;
    float4 xv = *(const float4*)&vc[(size_t)s * DD + d0];
    lt[d0 + 0][s] = (_Float16)xv.x;
    lt[d0 + 1][s] = (_Float16)xv.y;
    lt[d0 + 2][s] = (_Float16)xv.z;
    lt[d0 + 3][s] = (_Float16)xv.w;
  }
  __syncthreads();
#pragma unroll
  for (int it = 0; it < 8; ++it) {
    int flat = it * 256 + tid;  // 128d x 16 s-groups
    int d = flat >> 4, sg = flat & 15;
    *(f16x8*)&vT[((size_t)bh * DD + d) * NSEQ + c * CHK + sg * 8] =
        *(const f16x8*)&lt[d][sg * 8];
  }
}

// ---------------- k1: phi v5 (32-row tile, 256 thr, 4+ blocks/CU) --------------
__global__ __launch_bounds__(256, 4)
void phi_kernel(const float* __restrict__ q, const float* __restrict__ k,
                const float* __restrict__ b1, const float* __restrict__ b2,
                const _Float16* __restrict__ w1h, const _Float16* __restrict__ w2h,
                _Float16* __restrict__ qp, _Float16* __restrict__ kp) {
  __shared__ __align__(16) char smem[16896];
  _Float16 (*xs)[136] = (_Float16(*)[136])smem;   // [32][136]  8.7K phase1
  _Float16 (*hs)[264] = (_Float16(*)[264])smem;   // [32][264] 16.9K phase2
  _Float16 (*os)[264] = (_Float16(*)[264])smem;   // alias, epilogue
  int blk = blockIdx.x;
  bool isk = blk & 1;
  int rb = (blk >> 1) * 32;
  const float* src = isk ? k : q;
  _Float16* dst = isk ? kp : qp;
  int tid = threadIdx.x;
  int lane = tid & 63, wv = tid >> 6, lr = lane & 15, lq = lane >> 4;
  int wn = wv;  // each wave owns one 64-wide F-strip

  // biases are ks-invariant: hoist to regs early (overlaps staging)
  float bb1[4], bb2[4];
#pragma unroll
  for (int fn = 0; fn < 4; ++fn) {
    bb1[fn] = b1[wn * 64 + fn * 16 + lr];
    bb2[fn] = b2[wn * 64 + fn * 16 + lr];
  }

  // stage x (32x128 f32->f16)
#pragma unroll
  for (int it = 0; it < 4; ++it) {
    int flat = it * 256 + tid;  // 32 rows x 32 d-groups
    int r = flat >> 5, dg = flat & 31;
    float4 xv = *(const float4*)&src[(size_t)(rb + r) * DD + dg * 4];
    f16x4 hv = {(_Float16)xv.x, (_Float16)xv.y, (_Float16)xv.z, (_Float16)xv.w};
    *(f16x4*)&xs[r][dg * 4] = hv;
  }
  __syncthreads();

  // GEMM1: wave tile 32x64, K=128; B-frags from global (L2-resident)
  f32x4 acc[2][4] = {};
#pragma unroll
  for (int ks = 0; ks < 4; ++ks) {
    f16x8 bv[4];
#pragma unroll
    for (int fn = 0; fn < 4; ++fn)
      bv[fn] = *(const f16x8*)&w1h[(size_t)(wn * 64 + fn * 16 + lr) * DD + ks * 32 + lq * 8];
    f16x8 av[2];
#pragma unroll
    for (int im = 0; im < 2; ++im)
      av[im] = *(const f16x8*)&xs[im * 16 + lr][ks * 32 + lq * 8];
#pragma unroll
    for (int fn = 0; fn < 4; ++fn)
#pragma unroll
      for (int im = 0; im < 2; ++im) acc[im][fn] = MFMA16(av[im], bv[fn], acc[im][fn]);
  }
  __syncthreads();  // xs dead

  // hs = silu(acc + b1)
#pragma unroll
  for (int im = 0; im < 2; ++im)
#pragma unroll
    for (int fn = 0; fn < 4; ++fn) {
      int f = wn * 64 + fn * 16 + lr;
      int r0 = im * 16 + lq * 4;
#pragma unroll
      for (int r = 0; r < 4; ++r) {
        float xv = acc[im][fn][r] + bb1[fn];
        hs[r0 + r][f] = (_Float16)(xv * __builtin_amdgcn_rcpf(1.0f + __expf(-xv)));
      }
    }
  __syncthreads();

  // GEMM2: wave tile 32x64, K=256; B-frags from global (L2-resident)
  f32x4 ac2[2][4] = {};
#pragma unroll
  for (int ks = 0; ks < 8; ++ks) {
    f16x8 bv[4];
#pragma unroll
    for (int fn = 0; fn < 4; ++fn)
      bv[fn] = *(const f16x8*)&w2h[(size_t)(wn * 64 + fn * 16 + lr) * FF + ks * 32 + lq * 8];
    f16x8 av[2];
#pragma unroll
    for (int im = 0; im < 2; ++im)
      av[im] = *(const f16x8*)&hs[im * 16 + lr][ks * 32 + lq * 8];
#pragma unroll
    for (int fn = 0; fn < 4; ++fn)
#pragma unroll
      for (int im = 0; im < 2; ++im) ac2[im][fn] = MFMA16(av[im], bv[fn], ac2[im][fn]);
  }
  __syncthreads();  // hs dead

  // epilogue: row-major tile in LDS -> coalesced f16x8 stores
#pragma unroll
  for (int im = 0; im < 2; ++im)
#pragma unroll
    for (int fn = 0; fn < 4; ++fn) {
      int g = wn * 64 + fn * 16 + lr;
      int r0 = im * 16 + lq * 4;
#pragma unroll
      for (int r = 0; r < 4; ++r)
        os[r0 + r][g] = (_Float16)(ac2[im][fn][r] + bb2[fn]);
    }
  __syncthreads();
#pragma unroll
  for (int it = 0; it < 4; ++it) {
    int flat = it * 256 + tid;  // 32 rows x 32 col-groups
    int r = flat >> 5, cg = flat & 31;
    *(f16x8*)&dst[(size_t)(rb + r) * FF + cg * 8] = *(const f16x8*)&os[r][cg * 8];
  }
}

// ---------------- k2: S^T[d][f] per chunk (kp transposed in LDS) ----------------
__global__ __launch_bounds__(512, 2)
void s_kernel(const _Float16* __restrict__ vT, const _Float16* __restrict__ kp,
              _Float16* __restrict__ S) {
  __shared__ __align__(16) _Float16 vt[128][136];
  __shared__ __align__(16) _Float16 kt[256][136];  // kt[f][s ^ swz(f)]
  int blk = blockIdx.x;
  int c = blk & 31, bh = blk >> 5;
  int tid = threadIdx.x;
#pragma unroll
  for (int it = 0; it < 4; ++it) {
    int flat = it * 512 + tid;
    int d = flat >> 4, sg = flat & 15;
    *(f16x8*)&vt[d][sg * 8] = *(const f16x8*)&vT[((size_t)bh * DD + d) * NSEQ + c * CHK + sg * 8];
  }
  // stage kp chunk [128 s][256 f] transposed -> kt[f][s], XOR-swizzled on s
  // (linear kt[f][s] would put all 32 same-fg lanes in one bank: 544B f-stride)
#pragma unroll
  for (int it = 0; it < 8; ++it) {
    int flat = it * 512 + tid;  // 128 s x 32 f-groups
    int s = flat >> 5, fg = flat & 31;
    f16x8 kv = *(const f16x8*)&kp[((size_t)bh * NSEQ + c * CHK + s) * FF + fg * 8];
    int sw = (fg & 15) << 3;
#pragma unroll
    for (int j = 0; j < 8; ++j)
      kt[fg * 8 + j][s ^ sw] = kv[j];
  }
  __syncthreads();
  int lane = tid & 63, wv = tid >> 6, lr = lane & 15, lq = lane >> 4;
  int wmd = wv & 1, wnf = wv >> 1;
  f32x4 acc[4][4] = {};
#pragma unroll
  for (int ks = 0; ks < 4; ++ks) {
    f16x8 av[4];
#pragma unroll
    for (int im = 0; im < 4; ++im)
      av[im] = *(const f16x8*)&vt[wmd * 64 + im * 16 + lr][ks * 32 + lq * 8];
#pragma unroll
    for (int fn = 0; fn < 4; ++fn) {
      int F = wnf * 64 + fn * 16 + lr;
      f16x8 bv = *(const f16x8*)&kt[F][(ks * 32 + lq * 8) ^ (((F >> 3) & 15) << 3)];
#pragma unroll
      for (int im = 0; im < 4; ++im) acc[im][fn] = MFMA16(av[im], bv, acc[im][fn]);
    }
  }
  _Float16* Sp = S + ((size_t)bh * NC + c) * (size_t)(DD * FF);
#pragma unroll
  for (int im = 0; im < 4; ++im)
#pragma unroll
    for (int fn = 0; fn < 4; ++fn) {
      int f = wnf * 64 + fn * 16 + lr;
#pragma unroll
      for (int r = 0; r < 4; ++r) {
        int d = wmd * 64 + im * 16 + lq * 4 + r;
        Sp[(size_t)d * FF + f] = (_Float16)acc[im][fn][r];
      }
    }
}

// ---------------- k3: prefix->Wf, suffix in-place over S (becomes Wr) ------
__global__ void prefix_kernel(_Float16* S_Wr, _Float16* __restrict__ Wf) {
  size_t idx = (size_t)blockIdx.x * 256 + threadIdx.x;
  int bh = (int)(idx >> 15);
  int df = (int)(idx & 32767);
  size_t base = (size_t)bh * NC * 32768 + df;
  float vals[NC];
#pragma unroll
  for (int c = 0; c < NC; ++c) vals[c] = (float)S_Wr[base + (size_t)c * 32768];
  float run = 0.f;
#pragma unroll
  for (int c = 0; c < NC; ++c) { Wf[base + (size_t)c * 32768] = (_Float16)run; run += vals[c]; }
  run = 0.f;
#pragma unroll
  for (int c = NC - 1; c >= 0; --c) { S_Wr[base + (size_t)c * 32768] = (_Float16)run; run += vals[c]; }
}

// ---------------- k4: fused phase-2 scan (full chunk per block) ----------------
__global__ __launch_bounds__(512, 2)
void scan_kernel(const _Float16* __restrict__ qp, const _Float16* __restrict__ kp,
                 const _Float16* __restrict__ vT, const _Float16* __restrict__ Wf,
                 const _Float16* __restrict__ Wr, float* __restrict__ out) {
  __shared__ __align__(16) _Float16 vt[128][136];
  __shared__ __align__(16) _Float16 P[128][136];
  int blk = blockIdx.x;
  int c = blk & 31, bh = blk >> 5;
  const _Float16* qpc = qp + ((size_t)bh * NSEQ + c * CHK) * FF;
  const _Float16* kpc = kp + ((size_t)bh * NSEQ + c * CHK) * FF;
  int tid = threadIdx.x, lane = tid & 63, wv = tid >> 6, lr = lane & 15, lq = lane >> 4;
  int wm = wv & 3, wn = wv >> 2;  // wm: 4x32 rows; wn: 2x64 (s-half in A, d-half in B)

  // aq: 16 frags (reused by phase A and inter), batched but bounded
  f16x8 aq[2][8];
#pragma unroll
  for (int im = 0; im < 2; ++im)
#pragma unroll
    for (int ks = 0; ks < 8; ++ks)
      aq[im][ks] = *(const f16x8*)&qpc[(size_t)(wm * 32 + im * 16 + lr) * FF + ks * 32 + lq * 8];
  // stage vt (b128, conflict-free)
#pragma unroll
  for (int it = 0; it < 4; ++it) {
    int flat = it * 512 + tid;
    int d = flat >> 4, sg = flat & 15;
    *(f16x8*)&vt[d][sg * 8] = *(const f16x8*)&vT[((size_t)bh * DD + d) * NSEQ + c * CHK + sg * 8];
  }
  // Phase A: P = qp.kp^T with bk double-buffer over j
  f16x8 bk[2][8];
#pragma unroll
  for (int ks = 0; ks < 8; ++ks)
    bk[0][ks] = *(const f16x8*)&kpc[(size_t)(wn * 64 + lr) * FF + ks * 32 + lq * 8];
  f32x4 pacc[2][4] = {};
#pragma unroll
  for (int j = 0; j < 4; ++j) {
    int cur = j & 1;
    if (j < 3)
#pragma unroll
      for (int ks = 0; ks < 8; ++ks)
        bk[cur ^ 1][ks] = *(const f16x8*)&kpc[(size_t)(wn * 64 + (j + 1) * 16 + lr) * FF + ks * 32 + lq * 8];
#pragma unroll
    for (int ks = 0; ks < 8; ++ks)
#pragma unroll
      for (int im = 0; im < 2; ++im)
        pacc[im][j] = MFMA16(aq[im][ks], bk[cur][ks], pacc[im][j]);
  }
#pragma unroll
  for (int im = 0; im < 2; ++im)
#pragma unroll
    for (int j = 0; j < 4; ++j)
#pragma unroll
      for (int r = 0; r < 4; ++r)
        P[wm * 32 + im * 16 + lq * 4 + r][wn * 64 + j * 16 + lr] = (_Float16)pacc[im][j][r];

  // prefetch W frags for jd=0 (before barrier: overlaps P writes)
  const _Float16* Wfc = Wf + ((size_t)bh * NC + c) * (size_t)(DD * FF);
  const _Float16* Wrc = Wr + ((size_t)bh * NC + c) * (size_t)(DD * FF);
  f16x8 bf[8], br[8];
#pragma unroll
  for (int ks = 0; ks < 8; ++ks) {
    int d = wn * 64 + lr;
    bf[ks] = *(const f16x8*)&Wfc[(size_t)d * FF + ks * 32 + lq * 8];
    br[ks] = *(const f16x8*)&Wrc[(size_t)d * FF + ks * 32 + lq * 8];
  }
  __syncthreads();

  // Phase B: inter (q.W) per d-group; W prefetch 1 group ahead; intra interleaved
  f32x4 af[2][4] = {}, ar[2][4] = {};
#pragma unroll
  for (int jd = 0; jd < 4; ++jd) {
#pragma unroll
    for (int ks = 0; ks < 8; ++ks)
#pragma unroll
      for (int im = 0; im < 2; ++im) {
        af[im][jd] = MFMA16(aq[im][ks], bf[ks], af[im][jd]);
        ar[im][jd] = MFMA16(aq[im][ks], br[ks], ar[im][jd]);
      }
    if (jd < 3)
#pragma unroll
      for (int ks = 0; ks < 8; ++ks) {
        int d = wn * 64 + (jd + 1) * 16 + lr;
        bf[ks] = *(const f16x8*)&Wfc[(size_t)d * FF + ks * 32 + lq * 8];
        br[ks] = *(const f16x8*)&Wrc[(size_t)d * FF + ks * 32 + lq * 8];
      }
    // intra k-step ks=jd (LDS-only; covers W prefetch latency)
    {
      int ks = jd;
      f16x8 bv[4];
#pragma unroll
      for (int jd2 = 0; jd2 < 4; ++jd2)
        bv[jd2] = *(const f16x8*)&vt[wn * 64 + jd2 * 16 + lr][ks * 32 + lq * 8];
#pragma unroll
      for (int im = 0; im < 2; ++im) {
        int irow = wm * 32 + im * 16 + lr;
        f16x8 p = *(const f16x8*)&P[irow][ks * 32 + lq * 8];
        f16x8 pf = p, pr = p;
#pragma unroll
        for (int jj = 0; jj < 8; ++jj) {
          int s = ks * 32 + lq * 8 + jj;
          pf[jj] = (s <= irow) ? p[jj] : (_Float16)0.0f;
          pr[jj] = (s >= irow) ? p[jj] : (_Float16)0.0f;
        }
#pragma unroll
        for (int jd2 = 0; jd2 < 4; ++jd2) {
          af[im][jd2] = MFMA16(pf, bv[jd2], af[im][jd2]);
          ar[im][jd2] = MFMA16(pr, bv[jd2], ar[im][jd2]);
        }
      }
    }
  }

  // epilogue
  float* oc = out + ((size_t)bh * NSEQ + c * CHK) * DD;
#pragma unroll
  for (int im = 0; im < 2; ++im)
#pragma unroll
    for (int jd = 0; jd < 4; ++jd) {
      int d = wn * 64 + jd * 16 + lr;
#pragma unroll
      for (int r = 0; r < 4; ++r) {
        int il = wm * 32 + im * 16 + lq * 4 + r;
        int gi = c * CHK + il;
        oc[(size_t)il * DD + d] = af[im][jd][r] / (float)(gi + 1) + ar[im][jd][r] / (float)(NSEQ - gi);
      }
    }
}

// ---------------- launcher ----------------
extern "C" void kernel_launch(void* const* d_in, const int* in_sizes, int n_in,
                              void* d_out, int out_size, void* d_ws, size_t ws_size,
                              hipStream_t stream) {
  const float* q  = (const float*)d_in[0];
  const float* k  = (const float*)d_in[1];
  const float* v  = (const float*)d_in[2];
  const float* w1 = (const float*)d_in[3];
  const float* b1 = (const float*)d_in[4];
  const float* w2 = (const float*)d_in[5];
  const float* b2 = (const float*)d_in[6];
  float* out = (float*)d_out;

  char* ws = (char*)d_ws;
  const size_t SZ = 50331648ull;  // 24*4096*256*2B
  _Float16* w1h = (_Float16*)(ws);
  _Float16* w2h = (_Float16*)(ws + 65536);
  _Float16* qp  = (_Float16*)(ws + 196608);
  _Float16* kp  = (_Float16*)(ws + 196608 + SZ);
  _Float16* Wf  = (_Float16*)(ws + 196608 + 2 * SZ);
  _Float16* S   = (_Float16*)(ws + 196608 + 3 * SZ);  // reused in-place as Wr
  _Float16* vT  = (_Float16*)(ws + 196608 + 4 * SZ);  // 24MB
  _Float16* Wr  = S;

  prep_kernel<<<dim3(256), dim3(256), 0, stream>>>(w1, w2, w1h, w2h);
  vt_kernel<<<dim3(BH * NC), dim3(256), 0, stream>>>(v, vT);
  phi_kernel<<<dim3(2 * NROWS / 32), dim3(256), 0, stream>>>(q, k, b1, b2, w1h, w2h, qp, kp);
  s_kernel<<<dim3(BH * NC), dim3(512), 0, stream>>>(vT, kp, S);
  prefix_kernel<<<dim3(BH * DD * FF / 256), dim3(256), 0, stream>>>(S, Wf);
  scan_kernel<<<dim3(BH * NC), dim3(512), 0, stream>>>(qp, kp, vT, Wf, Wr, out);
}

// Round 7
// 441.951 us; speedup vs baseline: 1.0072x; 1.0072x over previous
//
#include <hip/hip_runtime.h>

// TTRFluxLayer R9: phi v7 — depth-2 named double-buffered weight pipeline.
// Same theory as R8 (R7 latency-bound: in-loop single-buffered weight loads,
// Mfma 9%/VALU 14%/HBM 11%). R8 (two 16-frag reg arrays, peak ~115/128 regs)
// failed twice at container level — possible allocator-thrash compile blowup.
// De-risked: depth-2 double buffers with NAMED arrays (bwA/bwB, rule #20):
//  * GEMM1: panels 0,1 issued BEFORE x-stage (drained by staging barrier);
//    panels 2,3 refilled one iter ahead.
//  * GEMM2: panels 0,1 issued before SiLU (hidden under VALU+barrier);
//    refill 2 ahead in-loop. Peak live ~90 regs under (512,4)=128 cap.
// k0 prep / k0b vt / k2 s (kp LDS-transpose) / k3 pfx / k4 scan: unchanged.
// ws: w1h 64K | w2h 128K | qp 48M | kp 48M | Wf 48M | S/Wr 48M | vT 24M

typedef __attribute__((ext_vector_type(8))) _Float16 f16x8;
typedef __attribute__((ext_vector_type(4))) _Float16 f16x4;
typedef __attribute__((ext_vector_type(4))) float f32x4;

#define MFMA16(a, b, c) __builtin_amdgcn_mfma_f32_16x16x32_f16((a), (b), (c), 0, 0, 0)

constexpr int BH   = 24;
constexpr int NSEQ = 4096;
constexpr int DD   = 128;
constexpr int FF   = 256;
constexpr int CHK  = 128;
constexpr int NC   = NSEQ / CHK;     // 32
constexpr int NROWS = BH * NSEQ;     // 98304

// ---------------- k0: weight convert ----------------
__global__ void prep_kernel(const float* __restrict__ w1, const float* __restrict__ w2,
                            _Float16* __restrict__ w1h, _Float16* __restrict__ w2h) {
  int i = blockIdx.x * 256 + threadIdx.x;
  if (i < FF * DD) w1h[i] = (_Float16)w1[i];
  if (i < FF * FF) w2h[i] = (_Float16)w2[i];
}

// ---------------- k0b: v -> vT fp16 [bh][d][s] ----------------
__global__ void vt_kernel(const float* __restrict__ v, _Float16* __restrict__ vT) {
  __shared__ __align__(16) _Float16 lt[128][136];
  int blk = blockIdx.x;
  int c = blk & 31, bh = blk >> 5;
  const float* vc = v + ((size_t)bh * NSEQ + c * CHK) * DD;
  int tid = threadIdx.x;
#pragma unroll
  for (int it = 0; it < 16; ++it) {
    int flat = it * 1024 + tid * 4;  // 128s x 128d
    int s = flat >> 7, d0 = flat & 127;
    float4 xv = *(const float4*)&vc[(size_t)s * DD + d0];
    lt[d0 + 0][s] = (_Float16)xv.x;
    lt[d0 + 1][s] = (_Float16)xv.y;
    lt[d0 + 2][s] = (_Float16)xv.z;
    lt[d0 + 3][s] = (_Float16)xv.w;
  }
  __syncthreads();
#pragma unroll
  for (int it = 0; it < 8; ++it) {
    int flat = it * 256 + tid;  // 128d x 16 s-groups
    int d = flat >> 4, sg = flat & 15;
    *(f16x8*)&vT[((size_t)bh * DD + d) * NSEQ + c * CHK + sg * 8] =
        *(const f16x8*)&lt[d][sg * 8];
  }
}

// ---------------- k1: phi v7 (64-row tile, 512 thr, depth-2 weight dbuf) ------
__global__ __launch_bounds__(512, 4)
void phi_kernel(const float* __restrict__ q, const float* __restrict__ k,
                const float* __restrict__ b1, const float* __restrict__ b2,
                const _Float16* __restrict__ w1h, const _Float16* __restrict__ w2h,
                _Float16* __restrict__ qp, _Float16* __restrict__ kp) {
  __shared__ __align__(16) char smem[33792];
  _Float16 (*xs)[136] = (_Float16(*)[136])smem;   // [64][136] 17.4K phase1
  _Float16 (*hs)[264] = (_Float16(*)[264])smem;   // [64][264] 33.8K phase2 (alias)
  _Float16 (*os)[264] = (_Float16(*)[264])smem;   // alias, epilogue
  int blk = blockIdx.x;
  bool isk = blk & 1;
  int rb = (blk >> 1) * 64;
  const float* src = isk ? k : q;
  _Float16* dst = isk ? kp : qp;
  int tid = threadIdx.x;
  int lane = tid & 63, wv = tid >> 6, lr = lane & 15, lq = lane >> 4;
  int wm = wv & 1, wn = wv >> 1;  // 2 row-strips(32) x 4 F-strips(64)

  const _Float16* w1row = w1h + (size_t)(wn * 64 + lr) * DD + lq * 8;
  const _Float16* w2row = w2h + (size_t)(wn * 64 + lr) * FF + lq * 8;

  // GEMM1 panels 0,1 issued FIRST: drained for free by the x-staging barrier
  f16x8 bwA[4], bwB[4];
#pragma unroll
  for (int fn = 0; fn < 4; ++fn) {
    bwA[fn] = *(const f16x8*)&w1row[(size_t)(fn * 16) * DD + 0 * 32];
    bwB[fn] = *(const f16x8*)&w1row[(size_t)(fn * 16) * DD + 1 * 32];
  }

  // biases hoisted (ks-invariant)
  float bb1[4], bb2[4];
#pragma unroll
  for (int fn = 0; fn < 4; ++fn) {
    bb1[fn] = b1[wn * 64 + fn * 16 + lr];
    bb2[fn] = b2[wn * 64 + fn * 16 + lr];
  }

  // stage x (64x128 f32->f16)
#pragma unroll
  for (int it = 0; it < 4; ++it) {
    int flat = it * 512 + tid;  // 64 rows x 32 d-groups
    int r = flat >> 5, dg = flat & 31;
    float4 xv = *(const float4*)&src[(size_t)(rb + r) * DD + dg * 4];
    f16x4 hv = {(_Float16)xv.x, (_Float16)xv.y, (_Float16)xv.z, (_Float16)xv.w};
    *(f16x4*)&xs[r][dg * 4] = hv;
  }
  __syncthreads();

  // GEMM1: wave tile 32x64, K=128; dbuf A/B, refill one iteration ahead
  f32x4 acc[2][4] = {};
#pragma unroll
  for (int p = 0; p < 2; ++p) {
    {  // ks = 2p (buffer A)
      f16x8 av[2];
#pragma unroll
      for (int im = 0; im < 2; ++im)
        av[im] = *(const f16x8*)&xs[wm * 32 + im * 16 + lr][(2 * p) * 32 + lq * 8];
#pragma unroll
      for (int fn = 0; fn < 4; ++fn)
#pragma unroll
        for (int im = 0; im < 2; ++im) acc[im][fn] = MFMA16(av[im], bwA[fn], acc[im][fn]);
      if (p < 1)
#pragma unroll
        for (int fn = 0; fn < 4; ++fn)
          bwA[fn] = *(const f16x8*)&w1row[(size_t)(fn * 16) * DD + (2 * p + 2) * 32];
    }
    {  // ks = 2p+1 (buffer B)
      f16x8 av[2];
#pragma unroll
      for (int im = 0; im < 2; ++im)
        av[im] = *(const f16x8*)&xs[wm * 32 + im * 16 + lr][(2 * p + 1) * 32 + lq * 8];
#pragma unroll
      for (int fn = 0; fn < 4; ++fn)
#pragma unroll
        for (int im = 0; im < 2; ++im) acc[im][fn] = MFMA16(av[im], bwB[fn], acc[im][fn]);
      if (p < 1)
#pragma unroll
        for (int fn = 0; fn < 4; ++fn)
          bwB[fn] = *(const f16x8*)&w1row[(size_t)(fn * 16) * DD + (2 * p + 3) * 32];
    }
  }
  __syncthreads();  // xs dead (hs aliases it)

  // GEMM2 panels 0,1 issued now: latency hidden by SiLU + barrier
  f16x8 cwA[4], cwB[4];
#pragma unroll
  for (int fn = 0; fn < 4; ++fn) {
    cwA[fn] = *(const f16x8*)&w2row[(size_t)(fn * 16) * FF + 0 * 32];
    cwB[fn] = *(const f16x8*)&w2row[(size_t)(fn * 16) * FF + 1 * 32];
  }

  // hs = silu(acc + b1)
#pragma unroll
  for (int im = 0; im < 2; ++im)
#pragma unroll
    for (int fn = 0; fn < 4; ++fn) {
      int f = wn * 64 + fn * 16 + lr;
      int r0 = wm * 32 + im * 16 + lq * 4;
#pragma unroll
      for (int r = 0; r < 4; ++r) {
        float xv = acc[im][fn][r] + bb1[fn];
        hs[r0 + r][f] = (_Float16)(xv * __builtin_amdgcn_rcpf(1.0f + __expf(-xv)));
      }
    }
  __syncthreads();

  // GEMM2: K=256, depth-2 dbuf, refill 2 panels ahead
  f32x4 ac2[2][4] = {};
#pragma unroll
  for (int p = 0; p < 4; ++p) {
    {  // ks = 2p (buffer A)
      f16x8 av[2];
#pragma unroll
      for (int im = 0; im < 2; ++im)
        av[im] = *(const f16x8*)&hs[wm * 32 + im * 16 + lr][(2 * p) * 32 + lq * 8];
#pragma unroll
      for (int fn = 0; fn < 4; ++fn)
#pragma unroll
        for (int im = 0; im < 2; ++im) ac2[im][fn] = MFMA16(av[im], cwA[fn], ac2[im][fn]);
      if (p < 3)
#pragma unroll
        for (int fn = 0; fn < 4; ++fn)
          cwA[fn] = *(const f16x8*)&w2row[(size_t)(fn * 16) * FF + (2 * p + 2) * 32];
    }
    {  // ks = 2p+1 (buffer B)
      f16x8 av[2];
#pragma unroll
      for (int im = 0; im < 2; ++im)
        av[im] = *(const f16x8*)&hs[wm * 32 + im * 16 + lr][(2 * p + 1) * 32 + lq * 8];
#pragma unroll
      for (int fn = 0; fn < 4; ++fn)
#pragma unroll
        for (int im = 0; im < 2; ++im) ac2[im][fn] = MFMA16(av[im], cwB[fn], ac2[im][fn]);
      if (p < 3)
#pragma unroll
        for (int fn = 0; fn < 4; ++fn)
          cwB[fn] = *(const f16x8*)&w2row[(size_t)(fn * 16) * FF + (2 * p + 3) * 32];
    }
  }
  __syncthreads();  // hs dead

  // epilogue: row-major tile in LDS -> coalesced f16x8 stores
#pragma unroll
  for (int im = 0; im < 2; ++im)
#pragma unroll
    for (int fn = 0; fn < 4; ++fn) {
      int g = wn * 64 + fn * 16 + lr;
      int r0 = wm * 32 + im * 16 + lq * 4;
#pragma unroll
      for (int r = 0; r < 4; ++r)
        os[r0 + r][g] = (_Float16)(ac2[im][fn][r] + bb2[fn]);
    }
  __syncthreads();
#pragma unroll
  for (int it = 0; it < 4; ++it) {
    int flat = it * 512 + tid;  // 64 rows x 32 col-groups
    int r = flat >> 5, cg = flat & 31;
    *(f16x8*)&dst[(size_t)(rb + r) * FF + cg * 8] = *(const f16x8*)&os[r][cg * 8];
  }
}

// ---------------- k2: S^T[d][f] per chunk (kp transposed in LDS) ----------------
__global__ __launch_bounds__(512, 2)
void s_kernel(const _Float16* __restrict__ vT, const _Float16* __restrict__ kp,
              _Float16* __restrict__ S) {
  __shared__ __align__(16) _Float16 vt[128][136];
  __shared__ __align__(16) _Float16 kt[256][136];  // kt[f][s ^ swz(f)]
  int blk = blockIdx.x;
  int c = blk & 31, bh = blk >> 5;
  int tid = threadIdx.x;
#pragma unroll
  for (int it = 0; it < 4; ++it) {
    int flat = it * 512 + tid;
    int d = flat >> 4, sg = flat & 15;
    *(f16x8*)&vt[d][sg * 8] = *(const f16x8*)&vT[((size_t)bh * DD + d) * NSEQ + c * CHK + sg * 8];
  }
  // stage kp chunk [128 s][256 f] transposed -> kt[f][s], XOR-swizzled on s
#pragma unroll
  for (int it = 0; it < 8; ++it) {
    int flat = it * 512 + tid;  // 128 s x 32 f-groups
    int s = flat >> 5, fg = flat & 31;
    f16x8 kv = *(const f16x8*)&kp[((size_t)bh * NSEQ + c * CHK + s) * FF + fg * 8];
    int sw = (fg & 15) << 3;
#pragma unroll
    for (int j = 0; j < 8; ++j)
      kt[fg * 8 + j][s ^ sw] = kv[j];
  }
  __syncthreads();
  int lane = tid & 63, wv = tid >> 6, lr = lane & 15, lq = lane >> 4;
  int wmd = wv & 1, wnf = wv >> 1;
  f32x4 acc[4][4] = {};
#pragma unroll
  for (int ks = 0; ks < 4; ++ks) {
    f16x8 av[4];
#pragma unroll
    for (int im = 0; im < 4; ++im)
      av[im] = *(const f16x8*)&vt[wmd * 64 + im * 16 + lr][ks * 32 + lq * 8];
#pragma unroll
    for (int fn = 0; fn < 4; ++fn) {
      int F = wnf * 64 + fn * 16 + lr;
      f16x8 bv = *(const f16x8*)&kt[F][(ks * 32 + lq * 8) ^ (((F >> 3) & 15) << 3)];
#pragma unroll
      for (int im = 0; im < 4; ++im) acc[im][fn] = MFMA16(av[im], bv, acc[im][fn]);
    }
  }
  _Float16* Sp = S + ((size_t)bh * NC + c) * (size_t)(DD * FF);
#pragma unroll
  for (int im = 0; im < 4; ++im)
#pragma unroll
    for (int fn = 0; fn < 4; ++fn) {
      int f = wnf * 64 + fn * 16 + lr;
#pragma unroll
      for (int r = 0; r < 4; ++r) {
        int d = wmd * 64 + im * 16 + lq * 4 + r;
        Sp[(size_t)d * FF + f] = (_Float16)acc[im][fn][r];
      }
    }
}

// ---------------- k3: prefix->Wf, suffix in-place over S (becomes Wr) ------
__global__ void prefix_kernel(_Float16* S_Wr, _Float16* __restrict__ Wf) {
  size_t idx = (size_t)blockIdx.x * 256 + threadIdx.x;
  int bh = (int)(idx >> 15);
  int df = (int)(idx & 32767);
  size_t base = (size_t)bh * NC * 32768 + df;
  float vals[NC];
#pragma unroll
  for (int c = 0; c < NC; ++c) vals[c] = (float)S_Wr[base + (size_t)c * 32768];
  float run = 0.f;
#pragma unroll
  for (int c = 0; c < NC; ++c) { Wf[base + (size_t)c * 32768] = (_Float16)run; run += vals[c]; }
  run = 0.f;
#pragma unroll
  for (int c = NC - 1; c >= 0; --c) { S_Wr[base + (size_t)c * 32768] = (_Float16)run; run += vals[c]; }
}

// ---------------- k4: fused phase-2 scan (full chunk per block) ----------------
__global__ __launch_bounds__(512, 2)
void scan_kernel(const _Float16* __restrict__ qp, const _Float16* __restrict__ kp,
                 const _Float16* __restrict__ vT, const _Float16* __restrict__ Wf,
                 const _Float16* __restrict__ Wr, float* __restrict__ out) {
  __shared__ __align__(16) _Float16 vt[128][136];
  __shared__ __align__(16) _Float16 P[128][136];
  int blk = blockIdx.x;
  int c = blk & 31, bh = blk >> 5;
  const _Float16* qpc = qp + ((size_t)bh * NSEQ + c * CHK) * FF;
  const _Float16* kpc = kp + ((size_t)bh * NSEQ + c * CHK) * FF;
  int tid = threadIdx.x, lane = tid & 63, wv = tid >> 6, lr = lane & 15, lq = lane >> 4;
  int wm = wv & 3, wn = wv >> 2;  // wm: 4x32 rows; wn: 2x64 (s-half in A, d-half in B)

  // aq: 16 frags (reused by phase A and inter), batched but bounded
  f16x8 aq[2][8];
#pragma unroll
  for (int im = 0; im < 2; ++im)
#pragma unroll
    for (int ks = 0; ks < 8; ++ks)
      aq[im][ks] = *(const f16x8*)&qpc[(size_t)(wm * 32 + im * 16 + lr) * FF + ks * 32 + lq * 8];
  // stage vt (b128, conflict-free)
#pragma unroll
  for (int it = 0; it < 4; ++it) {
    int flat = it * 512 + tid;
    int d = flat >> 4, sg = flat & 15;
    *(f16x8*)&vt[d][sg * 8] = *(const f16x8*)&vT[((size_t)bh * DD + d) * NSEQ + c * CHK + sg * 8];
  }
  // Phase A: P = qp.kp^T with bk double-buffer over j
  f16x8 bk[2][8];
#pragma unroll
  for (int ks = 0; ks < 8; ++ks)
    bk[0][ks] = *(const f16x8*)&kpc[(size_t)(wn * 64 + lr) * FF + ks * 32 + lq * 8];
  f32x4 pacc[2][4] = {};
#pragma unroll
  for (int j = 0; j < 4; ++j) {
    int cur = j & 1;
    if (j < 3)
#pragma unroll
      for (int ks = 0; ks < 8; ++ks)
        bk[cur ^ 1][ks] = *(const f16x8*)&kpc[(size_t)(wn * 64 + (j + 1) * 16 + lr) * FF + ks * 32 + lq * 8];
#pragma unroll
    for (int ks = 0; ks < 8; ++ks)
#pragma unroll
      for (int im = 0; im < 2; ++im)
        pacc[im][j] = MFMA16(aq[im][ks], bk[cur][ks], pacc[im][j]);
  }
#pragma unroll
  for (int im = 0; im < 2; ++im)
#pragma unroll
    for (int j = 0; j < 4; ++j)
#pragma unroll
      for (int r = 0; r < 4; ++r)
        P[wm * 32 + im * 16 + lq * 4 + r][wn * 64 + j * 16 + lr] = (_Float16)pacc[im][j][r];

  // prefetch W frags for jd=0 (before barrier: overlaps P writes)
  const _Float16* Wfc = Wf + ((size_t)bh * NC + c) * (size_t)(DD * FF);
  const _Float16* Wrc = Wr + ((size_t)bh * NC + c) * (size_t)(DD * FF);
  f16x8 bf[8], br[8];
#pragma unroll
  for (int ks = 0; ks < 8; ++ks) {
    int d = wn * 64 + lr;
    bf[ks] = *(const f16x8*)&Wfc[(size_t)d * FF + ks * 32 + lq * 8];
    br[ks] = *(const f16x8*)&Wrc[(size_t)d * FF + ks * 32 + lq * 8];
  }
  __syncthreads();

  // Phase B: inter (q.W) per d-group; W prefetch 1 group ahead; intra interleaved
  f32x4 af[2][4] = {}, ar[2][4] = {};
#pragma unroll
  for (int jd = 0; jd < 4; ++jd) {
#pragma unroll
    for (int ks = 0; ks < 8; ++ks)
#pragma unroll
      for (int im = 0; im < 2; ++im) {
        af[im][jd] = MFMA16(aq[im][ks], bf[ks], af[im][jd]);
        ar[im][jd] = MFMA16(aq[im][ks], br[ks], ar[im][jd]);
      }
    if (jd < 3)
#pragma unroll
      for (int ks = 0; ks < 8; ++ks) {
        int d = wn * 64 + (jd + 1) * 16 + lr;
        bf[ks] = *(const f16x8*)&Wfc[(size_t)d * FF + ks * 32 + lq * 8];
        br[ks] = *(const f16x8*)&Wrc[(size_t)d * FF + ks * 32 + lq * 8];
      }
    // intra k-step ks=jd (LDS-only; covers W prefetch latency)
    {
      int ks = jd;
      f16x8 bv[4];
#pragma unroll
      for (int jd2 = 0; jd2 < 4; ++jd2)
        bv[jd2] = *(const f16x8*)&vt[wn * 64 + jd2 * 16 + lr][ks * 32 + lq * 8];
#pragma unroll
      for (int im = 0; im < 2; ++im) {
        int irow = wm * 32 + im * 16 + lr;
        f16x8 p = *(const f16x8*)&P[irow][ks * 32 + lq * 8];
        f16x8 pf = p, pr = p;
#pragma unroll
        for (int jj = 0; jj < 8; ++jj) {
          int s = ks * 32 + lq * 8 + jj;
          pf[jj] = (s <= irow) ? p[jj] : (_Float16)0.0f;
          pr[jj] = (s >= irow) ? p[jj] : (_Float16)0.0f;
        }
#pragma unroll
        for (int jd2 = 0; jd2 < 4; ++jd2) {
          af[im][jd2] = MFMA16(pf, bv[jd2], af[im][jd2]);
          ar[im][jd2] = MFMA16(pr, bv[jd2], ar[im][jd2]);
        }
      }
    }
  }

  // epilogue
  float* oc = out + ((size_t)bh * NSEQ + c * CHK) * DD;
#pragma unroll
  for (int im = 0; im < 2; ++im)
#pragma unroll
    for (int jd = 0; jd < 4; ++jd) {
      int d = wn * 64 + jd * 16 + lr;
#pragma unroll
      for (int r = 0; r < 4; ++r) {
        int il = wm * 32 + im * 16 + lq * 4 + r;
        int gi = c * CHK + il;
        oc[(size_t)il * DD + d] = af[im][jd][r] / (float)(gi + 1) + ar[im][jd][r] / (float)(NSEQ - gi);
      }
    }
}

// ---------------- launcher ----------------
extern "C" void kernel_launch(void* const* d_in, const int* in_sizes, int n_in,
                              void* d_out, int out_size, void* d_ws, size_t ws_size,
                              hipStream_t stream) {
  const float* q  = (const float*)d_in[0];
  const float* k  = (const float*)d_in[1];
  const float* v  = (const float*)d_in[2];
  const float* w1 = (const float*)d_in[3];
  const float* b1 = (const float*)d_in[4];
  const float* w2 = (const float*)d_in[5];
  const float* b2 = (const float*)d_in[6];
  float* out = (float*)d_out;

  char* ws = (char*)d_ws;
  const size_t SZ = 50331648ull;  // 24*4096*256*2B
  _Float16* w1h = (_Float16*)(ws);
  _Float16* w2h = (_Float16*)(ws + 65536);
  _Float16* qp  = (_Float16*)(ws + 196608);
  _Float16* kp  = (_Float16*)(ws + 196608 + SZ);
  _Float16* Wf  = (_Float16*)(ws + 196608 + 2 * SZ);
  _Float16* S   = (_Float16*)(ws + 196608 + 3 * SZ);  // reused in-place as Wr
  _Float16* vT  = (_Float16*)(ws + 196608 + 4 * SZ);  // 24MB
  _Float16* Wr  = S;

  prep_kernel<<<dim3(256), dim3(256), 0, stream>>>(w1, w2, w1h, w2h);
  vt_kernel<<<dim3(BH * NC), dim3(256), 0, stream>>>(v, vT);
  phi_kernel<<<dim3(2 * NROWS / 64), dim3(512), 0, stream>>>(q, k, b1, b2, w1h, w2h, qp, kp);
  s_kernel<<<dim3(BH * NC), dim3(512), 0, stream>>>(vT, kp, S);
  prefix_kernel<<<dim3(BH * DD * FF / 256), dim3(256), 0, stream>>>(S, Wf);
  scan_kernel<<<dim3(BH * NC), dim3(512), 0, stream>>>(qp, kp, vT, Wf, Wr, out);
}